// Round 3
// baseline (410.791 us; speedup 1.0000x reference)
//
#include <hip/hip_runtime.h>

// MultiHeadSelfAttention: B=2, S=2048, E=768, H=12, D=64
// R3: R2 with the cvt_pkrtz type error fixed (plain _Float16 casts).
// Flash: S^T = K*Q^T so softmax is in-lane and P^T feeds PV
// (O^T = V^T * P^T, mfma 16x16x16 f16) from registers — no LDS, no barriers.
// GEMMs use global_load_lds width=16 (m97 pattern).

typedef __bf16 bf16_t;
typedef bf16_t bf16x8 __attribute__((ext_vector_type(8)));
typedef bf16_t bf16x4 __attribute__((ext_vector_type(4)));
typedef float f32x4 __attribute__((ext_vector_type(4)));
typedef _Float16 f16x4 __attribute__((ext_vector_type(4)));

#define SC2 0.1803368801111137f  // 0.125 * log2(e): fold qk-scale into exp2

__device__ __forceinline__ float bf2f(unsigned short u) {
  union { unsigned int i; float f; } x;
  x.i = ((unsigned int)u) << 16;
  return x.f;
}

__device__ __forceinline__ void glds16(const bf16_t* g, bf16_t* l) {
  __builtin_amdgcn_global_load_lds(
      (const __attribute__((address_space(1))) void*)g,
      (__attribute__((address_space(3))) void*)l, 16, 0, 0);
}

// ---------------------------------------------------------------- dtype probe
__global__ void k_detect(const unsigned short* __restrict__ x, int* __restrict__ flag) {
  int lane = threadIdx.x;
  int big = 0;
  for (int i = 0; i < 32; i++) {
    unsigned short u = x[lane + i * 64];
    int e = (u >> 7) & 0xFF;
    big |= (e > 0x88);
  }
  unsigned long long b = __ballot(big);
  if (lane == 0) *flag = (b == 0ULL) ? 1 : 0;  // 1 => inputs are bf16
}

// ---------------------------------------------------------------- x -> bf16
__global__ void k_ingest_x(const void* __restrict__ xsrc, const int* __restrict__ flag,
                           bf16_t* __restrict__ xb) {
  int i = blockIdx.x * 256 + threadIdx.x;
  if (*flag) {
    ((uint4*)xb)[i] = ((const uint4*)xsrc)[i];
  } else {
    const float* xf = (const float*)xsrc + (size_t)i * 8;
    bf16x8 v;
#pragma unroll
    for (int j = 0; j < 8; j++) v[j] = (bf16_t)xf[j];
    *(bf16x8*)(xb + (size_t)i * 8) = v;
  }
}

// ------------------------------------------------- W (768x768) -> W^T bf16
__global__ void k_wtrans(const void* __restrict__ wsrc, const int* __restrict__ flag,
                         bf16_t* __restrict__ dst, int rowOff) {
  __shared__ float ts[32][33];
  const int kt = blockIdx.x, nt = blockIdx.y;
  const int c = threadIdx.x & 31, r0 = threadIdx.x >> 5;
  const int f = *flag;
#pragma unroll
  for (int i = 0; i < 4; i++) {
    int kr = kt * 32 + r0 + i * 8;
    float v;
    if (f) v = bf2f(((const unsigned short*)wsrc)[(size_t)kr * 768 + nt * 32 + c]);
    else   v = ((const float*)wsrc)[(size_t)kr * 768 + nt * 32 + c];
    ts[r0 + i * 8][c] = v;
  }
  __syncthreads();
#pragma unroll
  for (int i = 0; i < 4; i++) {
    int nr = nt * 32 + r0 + i * 8;
    dst[(size_t)(rowOff + nr) * 768 + kt * 32 + c] = (bf16_t)ts[c][r0 + i * 8];
  }
}

// ---------------------------------------------------------------- bo -> f32
__global__ void k_ingest_bo(const void* __restrict__ src, const int* __restrict__ flag,
                            float* __restrict__ dst) {
  int i = blockIdx.x * 256 + threadIdx.x;
  if (i < 768) {
    if (*flag) dst[i] = bf2f(((const unsigned short*)src)[i]);
    else       dst[i] = ((const float*)src)[i];
  }
}

// ------------------------------------------- mask nonzero flags per 128x128
__global__ void k_maskflags(const void* __restrict__ mask, const int* __restrict__ flag,
                            int* __restrict__ mflags) {
  __shared__ int s;
  const int qt = blockIdx.x, kt = blockIdx.y;
  const int f = *flag;
  if (threadIdx.x == 0) s = 0;
  __syncthreads();
  int nz = 0;
  for (int i = 0; i < 64; i++) {
    int lin = i * 256 + threadIdx.x;
    int r = lin >> 7, c = lin & 127;
    size_t idx = (size_t)(qt * 128 + r) * 2048 + kt * 128 + c;
    float v = f ? bf2f(((const unsigned short*)mask)[idx]) : ((const float*)mask)[idx];
    nz |= (v != 0.0f);
  }
  if (nz) s = 1;
  __syncthreads();
  if (threadIdx.x == 0) mflags[qt * 16 + kt] = s;
}

// --------------------------------------------------------------------- GEMM
// C[M x N] = A[M x 768] * B^T[N x 768], 128x128 tile, m97 pattern:
// unpadded [128][32] LDS + global_load_lds width=16.
// MODE 0: N=2304: Q,K -> [b,h,s,d] bf16; V -> V^T [b,h,d,s] f16 via LDS transpose
// MODE 1: N=768 : + bias, write out (fp32 or bf16 per flag)
template <int MODE>
__global__ __launch_bounds__(256, 2) void k_gemm(
    const bf16_t* __restrict__ A, const bf16_t* __restrict__ Bm,
    bf16_t* __restrict__ Qd, bf16_t* __restrict__ Kd, _Float16* __restrict__ Vt,
    float* __restrict__ outF, unsigned short* __restrict__ outH,
    const float* __restrict__ bias, const int* __restrict__ flag) {
  __shared__ __align__(16) char smem[17408];  // As(8K)+Bs(8K); reused as 64x136 f16
  bf16_t* As = (bf16_t*)smem;
  bf16_t* Bs = (bf16_t*)(smem + 8192);
  _Float16* Tb = (_Float16*)smem;

  const int tid = threadIdx.x;
  const int n0 = blockIdx.x * 128, m0 = blockIdx.y * 128;
  const int r = tid >> 2, c8 = (tid & 3) << 3;
  const bf16_t* Ag = A + (size_t)(m0 + r) * 768 + c8;
  const bf16_t* Bg = Bm + (size_t)(n0 + r) * 768 + c8;
  const int wid = tid >> 6, lane = tid & 63;
  const int wm = (wid >> 1) << 6, wn = (wid & 1) << 6;
  const int lr = lane & 15, lk = (lane >> 4) << 3, g4 = (lane >> 4) << 2;

  f32x4 acc[4][4];
  const f32x4 z = {0.f, 0.f, 0.f, 0.f};
#pragma unroll
  for (int i = 0; i < 4; i++)
#pragma unroll
    for (int j = 0; j < 4; j++) acc[i][j] = z;

  for (int k0 = 0; k0 < 768; k0 += 32) {
    glds16(Ag + k0, As + wid * 512);
    glds16(Ag + (size_t)64 * 768 + k0, As + 2048 + wid * 512);
    glds16(Bg + k0, Bs + wid * 512);
    glds16(Bg + (size_t)64 * 768 + k0, Bs + 2048 + wid * 512);
    __syncthreads();
    bf16x8 af[4], bf_[4];
#pragma unroll
    for (int t = 0; t < 4; t++) af[t]  = *(const bf16x8*)&As[(wm + t * 16 + lr) * 32 + lk];
#pragma unroll
    for (int t = 0; t < 4; t++) bf_[t] = *(const bf16x8*)&Bs[(wn + t * 16 + lr) * 32 + lk];
#pragma unroll
    for (int i = 0; i < 4; i++)
#pragma unroll
      for (int j = 0; j < 4; j++)
        acc[i][j] = __builtin_amdgcn_mfma_f32_16x16x32_bf16(af[i], bf_[j], acc[i][j], 0, 0, 0);
    __syncthreads();
  }

  if (MODE == 1) {
    const int obf = *flag;
#pragma unroll
    for (int i = 0; i < 4; i++)
#pragma unroll
      for (int j = 0; j < 4; j++) {
        const int nn = n0 + wn + j * 16 + lr;
        const float bv = bias[nn];
#pragma unroll
        for (int reg = 0; reg < 4; reg++) {
          const int m = m0 + wm + i * 16 + g4 + reg;
          const float v = acc[i][j][reg] + bv;
          if (obf) outH[(size_t)m * 768 + nn] = __builtin_bit_cast(unsigned short, (bf16_t)v);
          else     outF[(size_t)m * 768 + nn] = v;
        }
      }
    return;
  }

  if (n0 < 1536) {  // ---- Q or K blocks: direct scatter (coalesced in 16-lane runs)
    bf16_t* dst = (n0 < 768) ? Qd : Kd;
    const int nb = (n0 < 768) ? n0 : n0 - 768;
    const int bb = m0 >> 11;
#pragma unroll
    for (int i = 0; i < 4; i++)
#pragma unroll
      for (int j = 0; j < 4; j++) {
        const int rc = nb + wn + j * 16 + lr;
        const int hh = rc >> 6, dd = rc & 63;
        const size_t base = (((size_t)bb * 12 + hh) * 2048) * 64 + dd;
#pragma unroll
        for (int reg = 0; reg < 4; reg++) {
          const int s = (m0 & 2047) + wm + i * 16 + g4 + reg;
          dst[base + (size_t)s * 64] = (bf16_t)acc[i][j][reg];
        }
      }
  } else {  // ---- V blocks: LDS transpose -> coalesced V^T f16 writes
    const int bb = m0 >> 11;
#pragma unroll
    for (int half = 0; half < 2; half++) {
      if ((wid & 1) == half) {
#pragma unroll
        for (int j = 0; j < 4; j++) {
          const int d_l = j * 16 + lr;
#pragma unroll
          for (int i = 0; i < 4; i++)
#pragma unroll
            for (int reg = 0; reg < 4; reg++)
              Tb[d_l * 136 + wm + i * 16 + g4 + reg] = (_Float16)acc[i][j][reg];
        }
      }
      __syncthreads();
      const int row = tid >> 2, cc = (tid & 3) * 32;
      const int vcol = (n0 - 1536) + half * 64 + row;
      const int hh = vcol >> 6;  // d == row
      _Float16* dstv = Vt + (((size_t)bb * 12 + hh) * 64 + row) * 2048 + (m0 & 2047) + cc;
#pragma unroll
      for (int u = 0; u < 4; u++)
        *(uint4*)(dstv + u * 8) = *(const uint4*)&Tb[row * 136 + cc + u * 8];
      __syncthreads();
    }
  }
}

// ----------------------------------------------------------- flash attention
// Grid (32 qtiles of 64, 12 heads, 2 batch), 256 thr = 4 indep waves, wave
// owns 16 q-rows. S^T = K*Q^T (C-layout: col=q, row=key) -> in-lane softmax
// (2 shfls) -> P^T packed f16 feeds O^T = V^T * P^T via mfma 16x16x16 f16.
// No LDS, no barriers.
__global__ __launch_bounds__(256, 3) void k_flash(
    const bf16_t* __restrict__ Qd, const bf16_t* __restrict__ Kd,
    const _Float16* __restrict__ Vt, const void* __restrict__ mask,
    const int* __restrict__ mflags, const int* __restrict__ flag,
    bf16_t* __restrict__ attn) {
  const int tid = threadIdx.x, wid = tid >> 6, lane = tid & 63;
  const int lr = lane & 15, quad = lane >> 4, lk = quad << 3, g4 = quad << 2;
  const int h = blockIdx.y, bb = blockIdx.z;
  const size_t bh = (size_t)bb * 12 + h;
  const bf16_t* Qh = Qd + bh * 2048 * 64;
  const bf16_t* Kbase = Kd + bh * 2048 * 64 + (size_t)lr * 64 + lk;
  const _Float16* Vbase = Vt + bh * 64 * 2048 + (size_t)lr * 2048 + g4;
  const int q0 = blockIdx.x * 64 + wid * 16;
  const int mbf = *flag;
  const int* mfrow = mflags + (blockIdx.x >> 1) * 16;

  const bf16x8 qf0 = *(const bf16x8*)&Qh[(size_t)(q0 + lr) * 64 + lk];
  const bf16x8 qf1 = *(const bf16x8*)&Qh[(size_t)(q0 + lr) * 64 + 32 + lk];

  const f32x4 z = {0.f, 0.f, 0.f, 0.f};
  f32x4 ot[4];
#pragma unroll
  for (int dt = 0; dt < 4; dt++) ot[dt] = z;
  float mrow = -1e30f, lrow = 0.f;

  for (int kt = 0; kt < 16; kt++) {
    // ---- S^T tiles: sv[ct] C-layout col=q(lr), row=key(ct*16+quad*4+reg)
    f32x4 sv[8];
#pragma unroll
    for (int ct = 0; ct < 8; ct++) sv[ct] = z;
#pragma unroll
    for (int ct = 0; ct < 8; ct++) {
      const bf16_t* Kp = Kbase + (size_t)(kt * 128 + ct * 16) * 64;
      bf16x8 kf0 = *(const bf16x8*)Kp;
      bf16x8 kf1 = *(const bf16x8*)(Kp + 32);
      sv[ct] = __builtin_amdgcn_mfma_f32_16x16x32_bf16(kf0, qf0, sv[ct], 0, 0, 0);
      sv[ct] = __builtin_amdgcn_mfma_f32_16x16x32_bf16(kf1, qf1, sv[ct], 0, 0, 0);
    }

    if (mfrow[kt]) {  // generic additive-mask path (skipped for zero mask)
#pragma unroll
      for (int ct = 0; ct < 8; ct++)
#pragma unroll
        for (int reg = 0; reg < 4; reg++) {
          size_t mi = (size_t)(q0 + lr) * 2048 + kt * 128 + ct * 16 + g4 + reg;
          float mv = mbf ? bf2f(((const unsigned short*)mask)[mi])
                         : ((const float*)mask)[mi];
          sv[ct][reg] -= 8e9f * mv;  // (-1e9 * mv) in pre-scale domain
        }
    }

    // ---- row max: in-lane tree over 32 regs, then xor-16/32 across quads
    float t01, t23;
    {
      float a = fmaxf(fmaxf(sv[0][0], sv[0][1]), fmaxf(sv[0][2], sv[0][3]));
      float b = fmaxf(fmaxf(sv[1][0], sv[1][1]), fmaxf(sv[1][2], sv[1][3]));
      float c = fmaxf(fmaxf(sv[2][0], sv[2][1]), fmaxf(sv[2][2], sv[2][3]));
      float d = fmaxf(fmaxf(sv[3][0], sv[3][1]), fmaxf(sv[3][2], sv[3][3]));
      float e = fmaxf(fmaxf(sv[4][0], sv[4][1]), fmaxf(sv[4][2], sv[4][3]));
      float f = fmaxf(fmaxf(sv[5][0], sv[5][1]), fmaxf(sv[5][2], sv[5][3]));
      float g = fmaxf(fmaxf(sv[6][0], sv[6][1]), fmaxf(sv[6][2], sv[6][3]));
      float hh2 = fmaxf(fmaxf(sv[7][0], sv[7][1]), fmaxf(sv[7][2], sv[7][3]));
      t01 = fmaxf(fmaxf(a, b), fmaxf(c, d));
      t23 = fmaxf(fmaxf(e, f), fmaxf(g, hh2));
    }
    float t = fmaxf(t01, t23);
    t = fmaxf(t, __shfl_xor(t, 16));
    t = fmaxf(t, __shfl_xor(t, 32));
    const float mnew = fmaxf(mrow, t);
    const float alpha = exp2f((mrow - mnew) * SC2);
    const float mS = mnew * SC2;
    mrow = mnew;

    // ---- P^T = exp(S^T - m) packed f16; row-sum
    float rs = 0.f;
    f16x4 pb[8];
#pragma unroll
    for (int ct = 0; ct < 8; ct++) {
      float p0 = exp2f(fmaf(sv[ct][0], SC2, -mS));
      float p1 = exp2f(fmaf(sv[ct][1], SC2, -mS));
      float p2 = exp2f(fmaf(sv[ct][2], SC2, -mS));
      float p3 = exp2f(fmaf(sv[ct][3], SC2, -mS));
      rs += (p0 + p1) + (p2 + p3);
      f16x4 pk;
      pk[0] = (_Float16)p0; pk[1] = (_Float16)p1;
      pk[2] = (_Float16)p2; pk[3] = (_Float16)p3;
      pb[ct] = pk;
    }
    rs += __shfl_xor(rs, 16);
    rs += __shfl_xor(rs, 32);
    lrow = lrow * alpha + rs;

    // ---- O^T rescale + accumulate: ot[dt] C-layout col=q, row=d(dt*16+quad*4+reg)
#pragma unroll
    for (int dt = 0; dt < 4; dt++)
#pragma unroll
      for (int reg = 0; reg < 4; reg++) ot[dt][reg] *= alpha;
#pragma unroll
    for (int ct = 0; ct < 8; ct++) {
#pragma unroll
      for (int dt = 0; dt < 4; dt++) {
        f16x4 va = *(const f16x4*)(Vbase + (size_t)(dt * 16) * 2048 + kt * 128 + ct * 16);
        ot[dt] = __builtin_amdgcn_mfma_f32_16x16x16f16(va, pb[ct], ot[dt], 0, 0, 0);
      }
    }
  }

  // ---- normalize + store: attn[b*2048+q][h*64+d], 4 contig d per (dt) -> 8B stores
  const float inv = 1.0f / lrow;
  bf16_t* arow = attn + ((size_t)bb * 2048 + q0 + lr) * 768 + h * 64 + g4;
#pragma unroll
  for (int dt = 0; dt < 4; dt++) {
    bf16x4 v;
#pragma unroll
    for (int reg = 0; reg < 4; reg++) v[reg] = (bf16_t)(ot[dt][reg] * inv);
    *(bf16x4*)(arow + dt * 16) = v;
  }
}

// -------------------------------------------------------------------- launch
extern "C" void kernel_launch(void* const* d_in, const int* in_sizes, int n_in,
                              void* d_out, int out_size, void* d_ws, size_t ws_size,
                              hipStream_t stream) {
  (void)in_sizes; (void)n_in; (void)out_size; (void)ws_size;
  const void* x    = d_in[0];
  const void* mask = d_in[1];
  const void* Wq   = d_in[2];
  const void* Wk   = d_in[3];
  const void* Wv   = d_in[4];
  const void* Wo   = d_in[5];
  const void* bo   = d_in[6];

  char* w = (char*)d_ws;
  size_t off = 0;
  auto take = [&](size_t b) -> void* {
    void* p = w + off;
    off = (off + b + 255) & ~(size_t)255;
    return p;
  };
  int*      flag   = (int*)take(4);
  int*      mflags = (int*)take(256 * 4);
  float*    boF    = (float*)take(768 * 4);
  bf16_t*   wqkvT  = (bf16_t*)take((size_t)2304 * 768 * 2);
  bf16_t*   woT    = (bf16_t*)take((size_t)768 * 768 * 2);
  bf16_t*   xb     = (bf16_t*)take((size_t)4096 * 768 * 2);
  bf16_t*   Qd     = (bf16_t*)take((size_t)3145728 * 2);
  bf16_t*   Kd     = (bf16_t*)take((size_t)3145728 * 2);
  _Float16* Vt     = (_Float16*)take((size_t)3145728 * 2);
  bf16_t*   attn   = xb;  // xb dead after GEMM1

  k_detect<<<1, 64, 0, stream>>>((const unsigned short*)x, flag);
  k_ingest_x<<<1536, 256, 0, stream>>>(x, flag, xb);
  k_wtrans<<<dim3(24, 24), 256, 0, stream>>>(Wq, flag, wqkvT, 0);
  k_wtrans<<<dim3(24, 24), 256, 0, stream>>>(Wk, flag, wqkvT, 768);
  k_wtrans<<<dim3(24, 24), 256, 0, stream>>>(Wv, flag, wqkvT, 1536);
  k_wtrans<<<dim3(24, 24), 256, 0, stream>>>(Wo, flag, woT, 0);
  k_ingest_bo<<<3, 256, 0, stream>>>(bo, flag, boF);
  k_maskflags<<<dim3(16, 16), 256, 0, stream>>>(mask, flag, mflags);
  k_gemm<0><<<dim3(18, 32), 256, 0, stream>>>(xb, wqkvT, Qd, Kd, Vt,
                                              nullptr, nullptr, nullptr, flag);
  k_flash<<<dim3(32, 12, 2), 256, 0, stream>>>(Qd, Kd, Vt, mask, mflags, flag, attn);
  k_gemm<1><<<dim3(6, 32), 256, 0, stream>>>(attn, woT, nullptr, nullptr, Vt,
                                             (float*)d_out, (unsigned short*)d_out,
                                             boF, flag);
}

// Round 4
// 218.481 us; speedup vs baseline: 1.8802x; 1.8802x over previous
//
#include <hip/hip_runtime.h>

// MultiHeadSelfAttention: B=2, S=2048, E=768, H=12, D=64
// R4: flash keeps R3's register-resident softmax (S^T = K*Q^T, P^T in regs)
//     but feeds K/V through LDS via global_load_lds DMA (no VGPR cost),
//     with DMA-time permuted layouts => conflict-free ds_read fragments.
//     GEMM2 retiled 64x64 for occupancy; launches merged 11 -> 7.

typedef __bf16 bf16_t;
typedef bf16_t bf16x8 __attribute__((ext_vector_type(8)));
typedef bf16_t bf16x4 __attribute__((ext_vector_type(4)));
typedef float f32x4 __attribute__((ext_vector_type(4)));
typedef _Float16 f16x4 __attribute__((ext_vector_type(4)));

#define SC2 0.1803368801111137f  // 0.125 * log2(e): qk-scale folded into exp2

__device__ __forceinline__ float bf2f(unsigned short u) {
  union { unsigned int i; float f; } x;
  x.i = ((unsigned int)u) << 16;
  return x.f;
}

__device__ __forceinline__ void glds16(const bf16_t* g, bf16_t* l) {
  __builtin_amdgcn_global_load_lds(
      (const __attribute__((address_space(1))) void*)g,
      (__attribute__((address_space(3))) void*)l, 16, 0, 0);
}
__device__ __forceinline__ void glds16b(const char* g, char* l) {
  __builtin_amdgcn_global_load_lds(
      (const __attribute__((address_space(1))) void*)g,
      (__attribute__((address_space(3))) void*)l, 16, 0, 0);
}

// ---------------------------------------------------------------- dtype probe
__global__ void k_detect(const unsigned short* __restrict__ x, int* __restrict__ flag) {
  int lane = threadIdx.x;
  int big = 0;
  for (int i = 0; i < 32; i++) {
    unsigned short u = x[lane + i * 64];
    int e = (u >> 7) & 0xFF;
    big |= (e > 0x88);
  }
  unsigned long long b = __ballot(big);
  if (lane == 0) *flag = (b == 0ULL) ? 1 : 0;  // 1 => inputs are bf16
}

// ---------------------------------------------------------------- x -> bf16
__global__ void k_ingest_x(const void* __restrict__ xsrc, const int* __restrict__ flag,
                           bf16_t* __restrict__ xb) {
  int i = blockIdx.x * 256 + threadIdx.x;
  if (*flag) {
    ((uint4*)xb)[i] = ((const uint4*)xsrc)[i];
  } else {
    const float* xf = (const float*)xsrc + (size_t)i * 8;
    bf16x8 v;
#pragma unroll
    for (int j = 0; j < 8; j++) v[j] = (bf16_t)xf[j];
    *(bf16x8*)(xb + (size_t)i * 8) = v;
  }
}

// ------------------------------------- W (768x768) -> W^T bf16 (all 4 in one)
__global__ void k_wtrans(const void* __restrict__ Wq, const void* __restrict__ Wk,
                         const void* __restrict__ Wv, const void* __restrict__ Wo,
                         const int* __restrict__ flag,
                         bf16_t* __restrict__ wqkvT, bf16_t* __restrict__ woT) {
  __shared__ float ts[32][33];
  const int z = blockIdx.z;
  const void* wsrc = (z == 0) ? Wq : (z == 1) ? Wk : (z == 2) ? Wv : Wo;
  bf16_t* dst = (z < 3) ? (wqkvT + (size_t)z * 768 * 768) : woT;
  const int kt = blockIdx.x, nt = blockIdx.y;
  const int c = threadIdx.x & 31, r0 = threadIdx.x >> 5;
  const int f = *flag;
#pragma unroll
  for (int i = 0; i < 4; i++) {
    int kr = kt * 32 + r0 + i * 8;
    float v;
    if (f) v = bf2f(((const unsigned short*)wsrc)[(size_t)kr * 768 + nt * 32 + c]);
    else   v = ((const float*)wsrc)[(size_t)kr * 768 + nt * 32 + c];
    ts[r0 + i * 8][c] = v;
  }
  __syncthreads();
#pragma unroll
  for (int i = 0; i < 4; i++) {
    int nr = nt * 32 + r0 + i * 8;
    dst[(size_t)nr * 768 + kt * 32 + c] = (bf16_t)ts[c][r0 + i * 8];
  }
}

// ------------------------------------------- mask nonzero flags per 128x128
__global__ void k_maskflags(const void* __restrict__ mask, const int* __restrict__ flag,
                            int* __restrict__ mflags) {
  __shared__ int s;
  const int qt = blockIdx.x, kt = blockIdx.y;
  const int f = *flag;
  if (threadIdx.x == 0) s = 0;
  __syncthreads();
  int nz = 0;
  for (int i = 0; i < 64; i++) {
    int lin = i * 256 + threadIdx.x;
    int r = lin >> 7, c = lin & 127;
    size_t idx = (size_t)(qt * 128 + r) * 2048 + kt * 128 + c;
    float v = f ? bf2f(((const unsigned short*)mask)[idx]) : ((const float*)mask)[idx];
    nz |= (v != 0.0f);
  }
  if (nz) s = 1;
  __syncthreads();
  if (threadIdx.x == 0) mflags[qt * 16 + kt] = s;
}

// ------------------------------------------------------------------ QKV GEMM
// C[4096 x 2304] = xb * wqkvT^T, 128x128 tile (m97 pattern).
// Epilogue: Q,K -> [b,h,s,d] bf16; V -> V^T [b,h,d,s] f16 via LDS transpose.
__global__ __launch_bounds__(256, 2) void k_gemmQKV(
    const bf16_t* __restrict__ A, const bf16_t* __restrict__ Bm,
    bf16_t* __restrict__ Qd, bf16_t* __restrict__ Kd, _Float16* __restrict__ Vt) {
  __shared__ __align__(16) char smem[17408];  // As(8K)+Bs(8K); reused 64x136 f16
  bf16_t* As = (bf16_t*)smem;
  bf16_t* Bs = (bf16_t*)(smem + 8192);
  _Float16* Tb = (_Float16*)smem;

  const int tid = threadIdx.x;
  const int n0 = blockIdx.x * 128, m0 = blockIdx.y * 128;
  const int r = tid >> 2, c8 = (tid & 3) << 3;
  const bf16_t* Ag = A + (size_t)(m0 + r) * 768 + c8;
  const bf16_t* Bg = Bm + (size_t)(n0 + r) * 768 + c8;
  const int wid = tid >> 6, lane = tid & 63;
  const int wm = (wid >> 1) << 6, wn = (wid & 1) << 6;
  const int lr = lane & 15, lk = (lane >> 4) << 3, g4 = (lane >> 4) << 2;

  f32x4 acc[4][4];
  const f32x4 z = {0.f, 0.f, 0.f, 0.f};
#pragma unroll
  for (int i = 0; i < 4; i++)
#pragma unroll
    for (int j = 0; j < 4; j++) acc[i][j] = z;

  for (int k0 = 0; k0 < 768; k0 += 32) {
    glds16(Ag + k0, As + wid * 512);
    glds16(Ag + (size_t)64 * 768 + k0, As + 2048 + wid * 512);
    glds16(Bg + k0, Bs + wid * 512);
    glds16(Bg + (size_t)64 * 768 + k0, Bs + 2048 + wid * 512);
    __syncthreads();
    bf16x8 af[4], bf_[4];
#pragma unroll
    for (int t = 0; t < 4; t++) af[t]  = *(const bf16x8*)&As[(wm + t * 16 + lr) * 32 + lk];
#pragma unroll
    for (int t = 0; t < 4; t++) bf_[t] = *(const bf16x8*)&Bs[(wn + t * 16 + lr) * 32 + lk];
#pragma unroll
    for (int i = 0; i < 4; i++)
#pragma unroll
      for (int j = 0; j < 4; j++)
        acc[i][j] = __builtin_amdgcn_mfma_f32_16x16x32_bf16(af[i], bf_[j], acc[i][j], 0, 0, 0);
    __syncthreads();
  }

  if (n0 < 1536) {  // Q or K: scatter (16-lane runs contiguous over d)
    bf16_t* dst = (n0 < 768) ? Qd : Kd;
    const int nb = (n0 < 768) ? n0 : n0 - 768;
    const int bb = m0 >> 11;
#pragma unroll
    for (int i = 0; i < 4; i++)
#pragma unroll
      for (int j = 0; j < 4; j++) {
        const int rc = nb + wn + j * 16 + lr;
        const int hh = rc >> 6, dd = rc & 63;
        const size_t base = (((size_t)bb * 12 + hh) * 2048) * 64 + dd;
#pragma unroll
        for (int reg = 0; reg < 4; reg++) {
          const int s = (m0 & 2047) + wm + i * 16 + g4 + reg;
          dst[base + (size_t)s * 64] = (bf16_t)acc[i][j][reg];
        }
      }
  } else {  // V: LDS transpose -> coalesced V^T f16 writes
    const int bb = m0 >> 11;
#pragma unroll
    for (int half = 0; half < 2; half++) {
      if ((wid & 1) == half) {
#pragma unroll
        for (int j = 0; j < 4; j++) {
          const int d_l = j * 16 + lr;
#pragma unroll
          for (int i = 0; i < 4; i++)
#pragma unroll
            for (int reg = 0; reg < 4; reg++)
              Tb[d_l * 136 + wm + i * 16 + g4 + reg] = (_Float16)acc[i][j][reg];
        }
      }
      __syncthreads();
      const int row = tid >> 2, cc = (tid & 3) * 32;
      const int vcol = (n0 - 1536) + half * 64 + row;
      const int hh = vcol >> 6;  // d == row
      _Float16* dstv = Vt + (((size_t)bb * 12 + hh) * 64 + row) * 2048 + (m0 & 2047) + cc;
#pragma unroll
      for (int u = 0; u < 4; u++)
        *(uint4*)(dstv + u * 8) = *(const uint4*)&Tb[row * 136 + cc + u * 8];
      __syncthreads();
    }
  }
}

// ----------------------------------------------------------- flash attention
// Grid 768 blocks (XCD-swizzled), 4 waves, wave owns 16 q-rows.
// Per kt: DMA-stage K(16KB)+V(16KB) into LDS in fragment-permuted layouts,
// then S^T = K*Q^T, in-lane softmax, O^T += V^T * P^T (P^T stays in regs).
__global__ __launch_bounds__(256, 3) void k_flash(
    const bf16_t* __restrict__ Qd, const bf16_t* __restrict__ Kd,
    const _Float16* __restrict__ Vt, const void* __restrict__ mask,
    const int* __restrict__ mflags, const int* __restrict__ flag,
    bf16_t* __restrict__ attn) {
  __shared__ __align__(16) char sm[32768];
  char* Ks = sm;          // 16 KB: unit16B[(ct*2+half)*64 + lr*4 + quad]
  char* Vs = sm + 16384;  // 16 KB: unit8B [(ct*4+dt )*64 + lr*4 + quad]

  const int tid = threadIdx.x, wid = tid >> 6, lane = tid & 63;
  const int lr = lane & 15, quad = lane >> 4, lk = quad << 3, g4 = quad << 2;

  // XCD swizzle: 96 consecutive-on-XCD slots = 3 heads x 32 qtiles
  const int lin = blockIdx.x + 32 * blockIdx.y + 384 * blockIdx.z;
  const int gx = lin & 7, ww = lin >> 3;
  const int hb = gx * 3 + (ww >> 5);
  const int h = hb % 12, bb = hb / 12;
  const int qt = ww & 31;

  const size_t bh = (size_t)bb * 12 + h;
  const bf16_t* Qh = Qd + bh * 2048 * 64;
  const char* Kh = (const char*)(Kd + bh * 2048 * 64);
  const char* Vh = (const char*)(Vt + bh * 64 * 2048);
  const int q0 = qt * 64 + wid * 16;
  const int mbf = *flag;
  const int* mfrow = mflags + (qt >> 1) * 16;

  const bf16x8 qf0 = *(const bf16x8*)&Qh[(size_t)(q0 + lr) * 64 + lk];
  const bf16x8 qf1 = *(const bf16x8*)&Qh[(size_t)(q0 + lr) * 64 + 32 + lk];

  // per-lane DMA source pointers (4 K wave-loads + 4 V wave-loads per wave)
  const char* Kp[4]; const char* Vp[4];
#pragma unroll
  for (int j = 0; j < 4; j++) {
    const int w = wid + 4 * j;
    const int R = ((w >> 1) << 4) + (lane >> 2);        // key row in tile
    const int ch = ((w & 1) << 2) + (lane & 3);         // 16B d-chunk
    Kp[j] = Kh + R * 128 + ch * 16;
    const int u2 = (w << 1) + (lane >> 5);              // ct*4+dt
    const int ctV = u2 >> 2, dtV = u2 & 3;
    const int D = (dtV << 4) + ((lane >> 1) & 15);      // d row
    Vp[j] = Vh + (size_t)D * 4096 + ctV * 32 + (lane & 1) * 16;
  }

  const int kbase = ((lr << 2) + quad) << 4;  // permuted slot *16B
  const int vbase = ((lr << 2) + quad) << 3;  // permuted slot *8B

  const f32x4 z = {0.f, 0.f, 0.f, 0.f};
  f32x4 ot[4];
#pragma unroll
  for (int dt = 0; dt < 4; dt++) ot[dt] = z;
  float mrow = -1e30f, lrow = 0.f;

  for (int kt = 0; kt < 16; kt++) {
#pragma unroll
    for (int j = 0; j < 4; j++) {
      glds16b(Kp[j] + kt * 16384, Ks + (wid + 4 * j) * 1024);
      glds16b(Vp[j] + kt * 256, Vs + (wid + 4 * j) * 1024);
    }
    __syncthreads();  // drains the DMA (vmcnt) + joins waves

    // ---- S^T: sv[ct] C-layout col=q(lr), row=key(ct*16+quad*4+reg)
    f32x4 sv[8];
#pragma unroll
    for (int ct = 0; ct < 8; ct++) sv[ct] = z;
#pragma unroll
    for (int ct = 0; ct < 8; ct++) {
      bf16x8 kf0 = *(const bf16x8*)(Ks + ct * 2048 + kbase);
      bf16x8 kf1 = *(const bf16x8*)(Ks + ct * 2048 + 1024 + kbase);
      sv[ct] = __builtin_amdgcn_mfma_f32_16x16x32_bf16(kf0, qf0, sv[ct], 0, 0, 0);
      sv[ct] = __builtin_amdgcn_mfma_f32_16x16x32_bf16(kf1, qf1, sv[ct], 0, 0, 0);
    }

    if (mfrow[kt]) {  // generic additive-mask path (skipped for zero mask)
#pragma unroll
      for (int ct = 0; ct < 8; ct++)
#pragma unroll
        for (int reg = 0; reg < 4; reg++) {
          size_t mi = (size_t)(q0 + lr) * 2048 + kt * 128 + ct * 16 + g4 + reg;
          float mv = mbf ? bf2f(((const unsigned short*)mask)[mi])
                         : ((const float*)mask)[mi];
          sv[ct][reg] -= 8e9f * mv;  // (-1e9*mv) in pre-scale domain
        }
    }

    // ---- row max: in-lane tree then xor-16/32 across quads
    float t01, t23;
    {
      float a = fmaxf(fmaxf(sv[0][0], sv[0][1]), fmaxf(sv[0][2], sv[0][3]));
      float b = fmaxf(fmaxf(sv[1][0], sv[1][1]), fmaxf(sv[1][2], sv[1][3]));
      float c = fmaxf(fmaxf(sv[2][0], sv[2][1]), fmaxf(sv[2][2], sv[2][3]));
      float d = fmaxf(fmaxf(sv[3][0], sv[3][1]), fmaxf(sv[3][2], sv[3][3]));
      float e = fmaxf(fmaxf(sv[4][0], sv[4][1]), fmaxf(sv[4][2], sv[4][3]));
      float f = fmaxf(fmaxf(sv[5][0], sv[5][1]), fmaxf(sv[5][2], sv[5][3]));
      float g = fmaxf(fmaxf(sv[6][0], sv[6][1]), fmaxf(sv[6][2], sv[6][3]));
      float hh2 = fmaxf(fmaxf(sv[7][0], sv[7][1]), fmaxf(sv[7][2], sv[7][3]));
      t01 = fmaxf(fmaxf(a, b), fmaxf(c, d));
      t23 = fmaxf(fmaxf(e, f), fmaxf(g, hh2));
    }
    float t = fmaxf(t01, t23);
    t = fmaxf(t, __shfl_xor(t, 16));
    t = fmaxf(t, __shfl_xor(t, 32));
    const float mnew = fmaxf(mrow, t);
    const float alpha = exp2f((mrow - mnew) * SC2);
    const float mS = mnew * SC2;
    mrow = mnew;

    // ---- P^T = exp2(S^T*SC2 - mS) packed f16; row-sum
    float rs = 0.f;
    f16x4 pb[8];
#pragma unroll
    for (int ct = 0; ct < 8; ct++) {
      float p0 = exp2f(fmaf(sv[ct][0], SC2, -mS));
      float p1 = exp2f(fmaf(sv[ct][1], SC2, -mS));
      float p2 = exp2f(fmaf(sv[ct][2], SC2, -mS));
      float p3 = exp2f(fmaf(sv[ct][3], SC2, -mS));
      rs += (p0 + p1) + (p2 + p3);
      f16x4 pk;
      pk[0] = (_Float16)p0; pk[1] = (_Float16)p1;
      pk[2] = (_Float16)p2; pk[3] = (_Float16)p3;
      pb[ct] = pk;
    }
    rs += __shfl_xor(rs, 16);
    rs += __shfl_xor(rs, 32);
    lrow = lrow * alpha + rs;

    // ---- O^T rescale + accumulate (V frags: stride-1 ds_read_b64)
#pragma unroll
    for (int dt = 0; dt < 4; dt++)
#pragma unroll
      for (int reg = 0; reg < 4; reg++) ot[dt][reg] *= alpha;
#pragma unroll
    for (int ct = 0; ct < 8; ct++) {
#pragma unroll
      for (int dt = 0; dt < 4; dt++) {
        f16x4 va = *(const f16x4*)(Vs + ((ct << 2) + dt) * 512 + vbase);
        ot[dt] = __builtin_amdgcn_mfma_f32_16x16x16f16(va, pb[ct], ot[dt], 0, 0, 0);
      }
    }
    __syncthreads();  // protect LDS from next kt's DMA
  }

  // ---- normalize + store attn[b*2048+q][h*64+d]
  const float inv = 1.0f / lrow;
  bf16_t* arow = attn + ((size_t)bb * 2048 + q0 + lr) * 768 + h * 64 + g4;
#pragma unroll
  for (int dt = 0; dt < 4; dt++) {
    bf16x4 v;
#pragma unroll
    for (int reg = 0; reg < 4; reg++) v[reg] = (bf16_t)(ot[dt][reg] * inv);
    *(bf16x4*)(arow + dt * 16) = v;
  }
}

// -------------------------------------------------- output GEMM (attn @ Wo^T)
// 64x64 tiles -> 768 blocks (3/CU). Bias read raw (dtype branch) in epilogue.
__global__ __launch_bounds__(256, 3) void k_gemm2(
    const bf16_t* __restrict__ A, const bf16_t* __restrict__ Bm,
    const void* __restrict__ bo, float* __restrict__ outF,
    unsigned short* __restrict__ outH, const int* __restrict__ flag) {
  __shared__ __align__(16) bf16_t As[64 * 32];
  __shared__ __align__(16) bf16_t Bs[64 * 32];
  const int tid = threadIdx.x;
  const int n0 = blockIdx.x * 64, m0 = blockIdx.y * 64;
  const int wid = tid >> 6, lane = tid & 63;
  const int wm = (wid >> 1) << 5, wn = (wid & 1) << 5;
  const int lr = lane & 15, lk = (lane >> 4) << 3, g4 = (lane >> 4) << 2;
  const bf16_t* Ag = A + (size_t)(m0 + wid * 16 + (lane >> 2)) * 768 + ((lane & 3) << 3);
  const bf16_t* Bg = Bm + (size_t)(n0 + wid * 16 + (lane >> 2)) * 768 + ((lane & 3) << 3);

  f32x4 acc[2][2];
  const f32x4 z = {0.f, 0.f, 0.f, 0.f};
#pragma unroll
  for (int i = 0; i < 2; i++)
#pragma unroll
    for (int j = 0; j < 2; j++) acc[i][j] = z;

  for (int k0 = 0; k0 < 768; k0 += 32) {
    glds16(Ag + k0, As + wid * 512);
    glds16(Bg + k0, Bs + wid * 512);
    __syncthreads();
    bf16x8 af[2], bf_[2];
#pragma unroll
    for (int i = 0; i < 2; i++) af[i]  = *(const bf16x8*)&As[(wm + i * 16 + lr) * 32 + lk];
#pragma unroll
    for (int j = 0; j < 2; j++) bf_[j] = *(const bf16x8*)&Bs[(wn + j * 16 + lr) * 32 + lk];
#pragma unroll
    for (int i = 0; i < 2; i++)
#pragma unroll
      for (int j = 0; j < 2; j++)
        acc[i][j] = __builtin_amdgcn_mfma_f32_16x16x32_bf16(af[i], bf_[j], acc[i][j], 0, 0, 0);
    __syncthreads();
  }

  const int obf = *flag;
#pragma unroll
  for (int i = 0; i < 2; i++)
#pragma unroll
    for (int j = 0; j < 2; j++) {
      const int nn = n0 + wn + j * 16 + lr;
      const float bv = obf ? bf2f(((const unsigned short*)bo)[nn])
                           : ((const float*)bo)[nn];
#pragma unroll
      for (int reg = 0; reg < 4; reg++) {
        const int m = m0 + wm + i * 16 + g4 + reg;
        const float v = acc[i][j][reg] + bv;
        if (obf) outH[(size_t)m * 768 + nn] = __builtin_bit_cast(unsigned short, (bf16_t)v);
        else     outF[(size_t)m * 768 + nn] = v;
      }
    }
}

// -------------------------------------------------------------------- launch
extern "C" void kernel_launch(void* const* d_in, const int* in_sizes, int n_in,
                              void* d_out, int out_size, void* d_ws, size_t ws_size,
                              hipStream_t stream) {
  (void)in_sizes; (void)n_in; (void)out_size; (void)ws_size;
  const void* x    = d_in[0];
  const void* mask = d_in[1];
  const void* Wq   = d_in[2];
  const void* Wk   = d_in[3];
  const void* Wv   = d_in[4];
  const void* Wo   = d_in[5];
  const void* bo   = d_in[6];

  char* w = (char*)d_ws;
  size_t off = 0;
  auto take = [&](size_t b) -> void* {
    void* p = w + off;
    off = (off + b + 255) & ~(size_t)255;
    return p;
  };
  int*      flag   = (int*)take(4);
  int*      mflags = (int*)take(256 * 4);
  bf16_t*   wqkvT  = (bf16_t*)take((size_t)2304 * 768 * 2);
  bf16_t*   woT    = (bf16_t*)take((size_t)768 * 768 * 2);
  bf16_t*   xb     = (bf16_t*)take((size_t)4096 * 768 * 2);
  bf16_t*   Qd     = (bf16_t*)take((size_t)3145728 * 2);
  bf16_t*   Kd     = (bf16_t*)take((size_t)3145728 * 2);
  _Float16* Vt     = (_Float16*)take((size_t)3145728 * 2);
  bf16_t*   attn   = xb;  // xb dead after GEMM1

  k_detect<<<1, 64, 0, stream>>>((const unsigned short*)x, flag);
  k_ingest_x<<<1536, 256, 0, stream>>>(x, flag, xb);
  k_wtrans<<<dim3(24, 24, 4), 256, 0, stream>>>(Wq, Wk, Wv, Wo, flag, wqkvT, woT);
  k_maskflags<<<dim3(16, 16), 256, 0, stream>>>(mask, flag, mflags);
  k_gemmQKV<<<dim3(18, 32), 256, 0, stream>>>(xb, wqkvT, Qd, Kd, Vt);
  k_flash<<<dim3(32, 12, 2), 256, 0, stream>>>(Qd, Kd, Vt, mask, mflags, flag, attn);
  k_gemm2<<<dim3(12, 64), 256, 0, stream>>>(attn, woT, bo, (float*)d_out,
                                            (unsigned short*)d_out, flag);
}